// Round 1
// baseline (543.841 us; speedup 1.0000x reference)
//
#include <hip/hip_runtime.h>
#include <stdint.h>

// ---------------- problem constants (b=1, f=8, h=16, w=32) ----------------
#define S_TOK 4096
#define DIM   2304
#define NH    24
#define DH    96
#define GQ    1024     // sparse sequence length (4096/4)
#define KDIM  2304

typedef unsigned short ushort_t;
typedef __attribute__((ext_vector_type(8))) short bf16x8;   // 8 bf16 = 4 VGPRs
typedef __attribute__((ext_vector_type(4))) float f32x4;

__device__ __forceinline__ ushort_t f2bf(float x) {
    union { float f; uint32_t u; } c; c.f = x;
    uint32_t u = c.u + 0x7FFFu + ((c.u >> 16) & 1u);   // RNE
    return (ushort_t)(u >> 16);
}

// ---------------- elementwise cast fp32 -> bf16 ----------------
__global__ __launch_bounds__(256) void cast_bf16_kernel(const float* __restrict__ in,
                                                        ushort_t* __restrict__ out, int n4) {
    int i = blockIdx.x * 256 + threadIdx.x;
    if (i >= n4) return;
    float4 v = ((const float4*)in)[i];
    ushort4 o;
    o.x = f2bf(v.x); o.y = f2bf(v.y); o.z = f2bf(v.z); o.w = f2bf(v.w);
    ((ushort4*)out)[i] = o;
}

// ---------------- W [k][n] fp32 -> WT [n][k] bf16 (tiled transpose) ----------------
__global__ __launch_bounds__(256) void wtrans_kernel(const float* __restrict__ W,
                                                     ushort_t* __restrict__ WT, int dim) {
    __shared__ float tile[32][33];
    const int bx = blockIdx.x * 32;   // n block
    const int by = blockIdx.y * 32;   // k block
    const int tx = threadIdx.x & 31, ty = threadIdx.x >> 5;
#pragma unroll
    for (int i = 0; i < 4; ++i)
        tile[ty + i*8][tx] = W[(size_t)(by + ty + i*8) * dim + bx + tx];
    __syncthreads();
#pragma unroll
    for (int i = 0; i < 4; ++i)
        WT[(size_t)(bx + ty + i*8) * dim + by + tx] = f2bf(tile[tx][ty + i*8]);
}

// ---------------- GEMM: C[m][n] = sum_k A[m][k]*Bt[n][k] + bias[n] ----------------
// m97 structure: 128x128 tile, BK=32, 4 waves (2x2), 16x16x32 bf16 MFMA,
// global_load_lds width 16.  Fused epilogues:
//   MODE 0: Q -> rope3d * 1/sqrt(96) -> [4][24][1024][96] bf16
//   MODE 1: K -> rope3d              -> [4][24][1024][96] bf16
//   MODE 2: V -> reorder             -> [4][24][1024][96] bf16
//   MODE 3: fp32 row-major C (final output)
#define GLDS(gp, lp) __builtin_amdgcn_global_load_lds( \
    (const __attribute__((address_space(1))) void*)(gp), \
    (__attribute__((address_space(3))) void*)(lp), 16, 0, 0)

template<int MODE>
__global__ __launch_bounds__(256) void gemm_bt(const ushort_t* __restrict__ A,
                                               const ushort_t* __restrict__ Bt,
                                               const float* __restrict__ bias,
                                               void* __restrict__ outp) {
    constexpr int K = KDIM;
    __shared__ ushort_t a_s[128 * 32];
    __shared__ ushort_t b_s[128 * 32];
    const int t  = threadIdx.x;
    const int l  = t & 63, w = t >> 6;
    const int wr = w >> 1, wc = w & 1;
    const int g  = l >> 4, ln = l & 15;
    const int m0 = blockIdx.y * 128, n0 = blockIdx.x * 128;

    const ushort_t* Ab = A  + (size_t)(m0 + (t >> 2)) * K + (t & 3) * 8;
    const ushort_t* Bb = Bt + (size_t)(n0 + (t >> 2)) * K + (t & 3) * 8;
    ushort_t* a_d0 = a_s + t * 8;
    ushort_t* a_d1 = a_s + 2048 + t * 8;
    ushort_t* b_d0 = b_s + t * 8;
    ushort_t* b_d1 = b_s + 2048 + t * 8;
    const size_t rstep = (size_t)64 * K;

    f32x4 acc[4][4] = {};

    for (int k0 = 0; k0 < K; k0 += 32) {
        __syncthreads();
        GLDS(Ab + k0,         a_d0);
        GLDS(Ab + rstep + k0, a_d1);
        GLDS(Bb + k0,         b_d0);
        GLDS(Bb + rstep + k0, b_d1);
        __syncthreads();
        bf16x8 av[4], bv[4];
#pragma unroll
        for (int i = 0; i < 4; ++i)
            av[i] = *(const bf16x8*)&a_s[(wr*64 + i*16 + ln) * 32 + g * 8];
#pragma unroll
        for (int j = 0; j < 4; ++j)
            bv[j] = *(const bf16x8*)&b_s[(wc*64 + j*16 + ln) * 32 + g * 8];
#pragma unroll
        for (int i = 0; i < 4; ++i)
#pragma unroll
            for (int j = 0; j < 4; ++j)
                acc[i][j] = __builtin_amdgcn_mfma_f32_16x16x32_bf16(av[i], bv[j], acc[i][j], 0, 0, 0);
    }

    if constexpr (MODE == 3) {
        float* C = (float*)outp;
#pragma unroll
        for (int i = 0; i < 4; ++i) {
            int mb = m0 + wr*64 + i*16 + g*4;
#pragma unroll
            for (int j = 0; j < 4; ++j) {
                int n = n0 + wc*64 + j*16 + ln;
                float bb = bias[n];
#pragma unroll
                for (int r = 0; r < 4; ++r)
                    C[(size_t)(mb + r) * DIM + n] = acc[i][j][r] + bb;
            }
        }
    } else if constexpr (MODE == 2) {
        ushort_t* O = (ushort_t*)outp;
#pragma unroll
        for (int i = 0; i < 4; ++i) {
            int mb = m0 + wr*64 + i*16 + g*4;
#pragma unroll
            for (int j = 0; j < 4; ++j) {
                int n = n0 + wc*64 + j*16 + ln;
                int h = n / DH, d = n - h * DH;
                float bb = bias[n];
#pragma unroll
                for (int r = 0; r < 4; ++r) {
                    int m = mb + r;
                    size_t o = ((size_t)((m & 3) * NH + h)) * (GQ * DH) + (size_t)(m >> 2) * DH + d;
                    O[o] = f2bf(acc[i][j][r] + bb);
                }
            }
        }
    } else {
        // Q (MODE 0) / K (MODE 1): fused 3D rope + sparse reorder.
        // pair (d1, d1+16) lives in adjacent even/odd 16-col tiles (j, j+1).
        const float scq = (MODE == 0) ? 0.1020620726159658f : 1.0f;  // 1/sqrt(96)
        ushort_t* O = (ushort_t*)outp;
#pragma unroll
        for (int i = 0; i < 4; ++i) {
            int mb = m0 + wr*64 + i*16 + g*4;
#pragma unroll
            for (int jp = 0; jp < 2; ++jp) {
                int j  = jp * 2;
                int n1 = n0 + wc*64 + j*16 + ln;       // even absolute 16-tile -> d1%32 < 16
                int h  = n1 / DH, d1 = n1 - h * DH;    // d1 in {0..15,32..47,64..79}
                int sec = d1 >> 5, f = d1 & 15;
                float invf = __expf((float)f * -0.5756462732485114f);  // 10000^(-f/16)
                float b1 = bias[n1], b2 = bias[n1 + 16];
#pragma unroll
                for (int r = 0; r < 4; ++r) {
                    int m = mb + r;                          // token index
                    int pos = (sec == 0) ? (m >> 9) : (sec == 1) ? ((m >> 5) & 15) : (m & 31);
                    float ang = (float)pos * invf;
                    float sn, cs;
                    __sincosf(ang, &sn, &cs);
                    float v1 = acc[i][j][r]     + b1;
                    float v2 = acc[i][j + 1][r] + b2;
                    float o1 = (v1 * cs - v2 * sn) * scq;
                    float o2 = (v2 * cs + v1 * sn) * scq;
                    size_t base = ((size_t)((m & 3) * NH + h)) * (GQ * DH) + (size_t)(m >> 2) * DH;
                    O[base + d1]      = f2bf(o1);
                    O[base + d1 + 16] = f2bf(o2);
                }
            }
        }
    }
}

// ---------------- flash attention over 96 instances of [1024,96] ----------------
// block = (instance, 64 q rows), 4 waves x 16 rows; KV tile = 64 keys.
__global__ __launch_bounds__(256) void attn_kernel(const ushort_t* __restrict__ Qb,
                                                   const ushort_t* __restrict__ Kb,
                                                   const ushort_t* __restrict__ Vb,
                                                   ushort_t* __restrict__ ATT) {
    __shared__ ushort_t k_s[64 * 104];     // K tile, row-major, stride 104
    __shared__ ushort_t vt_s[96 * 72];     // V^T tile: [d][key], stride 72
    __shared__ ushort_t p_s[4 * 16 * 72];  // per-wave P, [q_local][key], stride 72

    const int t = threadIdx.x, l = t & 63, w = t >> 6, g = l >> 4, ln = l & 15;
    const int inst = blockIdx.x;           // n_idx*24 + h
    const int qb0  = blockIdx.y * 64;
    const ushort_t* Qi = Qb + (size_t)inst * (GQ * DH);
    const ushort_t* Ki = Kb + (size_t)inst * (GQ * DH);
    const ushort_t* Vi = Vb + (size_t)inst * (GQ * DH);

    // hoist Q fragments (A operand) straight from global; Q already has 1/sqrt(96)
    bf16x8 qf[3];
    {
        int qrow = qb0 + w * 16 + ln;
#pragma unroll
        for (int ks = 0; ks < 3; ++ks)
            qf[ks] = *(const bf16x8*)(Qi + (size_t)qrow * DH + ks * 32 + g * 8);
    }

    float m_run[4], l_run[4];
#pragma unroll
    for (int r = 0; r < 4; ++r) { m_run[r] = -3.0e38f; l_run[r] = 0.f; }
    f32x4 acc_o[6] = {};

    for (int kt = 0; kt < 16; ++kt) {
        __syncthreads();
        // stage K (row-major) and V^T
#pragma unroll
        for (int it = 0; it < 6; ++it) {
            int idx = t + it * 256;            // 0..1535
            int row = idx / 24;                // key 0..63 within tile
            int col = (idx - row * 24) * 4;    // d
            const size_t gp = ((size_t)(kt * 64 + row)) * DH + col;
            ushort4 kv = *(const ushort4*)(Ki + gp);
            *(ushort4*)&k_s[row * 104 + col] = kv;
            ushort4 vv = *(const ushort4*)(Vi + gp);
            vt_s[(col + 0) * 72 + row] = vv.x;
            vt_s[(col + 1) * 72 + row] = vv.y;
            vt_s[(col + 2) * 72 + row] = vv.z;
            vt_s[(col + 3) * 72 + row] = vv.w;
        }
        __syncthreads();

        // S = Q K^T  (C layout: col=key=ln, row=q=g*4+r)
        f32x4 sc4[4] = {};
#pragma unroll
        for (int ct = 0; ct < 4; ++ct)
#pragma unroll
            for (int ks = 0; ks < 3; ++ks) {
                bf16x8 kf = *(const bf16x8*)&k_s[(ct * 16 + ln) * 104 + ks * 32 + g * 8];
                sc4[ct] = __builtin_amdgcn_mfma_f32_16x16x32_bf16(qf[ks], kf, sc4[ct], 0, 0, 0);
            }

        // online softmax (rows live across the 16 lanes of each l>>4 group)
        float mx[4];
#pragma unroll
        for (int r = 0; r < 4; ++r)
            mx[r] = fmaxf(fmaxf(sc4[0][r], sc4[1][r]), fmaxf(sc4[2][r], sc4[3][r]));
#pragma unroll
        for (int off = 1; off < 16; off <<= 1)
#pragma unroll
            for (int r = 0; r < 4; ++r)
                mx[r] = fmaxf(mx[r], __shfl_xor(mx[r], off, 64));
        float al[4], rs[4], p[4][4];
#pragma unroll
        for (int r = 0; r < 4; ++r) {
            float mn = fmaxf(m_run[r], mx[r]);
            al[r] = __expf(m_run[r] - mn);
            m_run[r] = mn;
            rs[r] = 0.f;
        }
#pragma unroll
        for (int ct = 0; ct < 4; ++ct)
#pragma unroll
            for (int r = 0; r < 4; ++r) {
                p[ct][r] = __expf(sc4[ct][r] - m_run[r]);
                rs[r] += p[ct][r];
            }
#pragma unroll
        for (int off = 1; off < 16; off <<= 1)
#pragma unroll
            for (int r = 0; r < 4; ++r)
                rs[r] += __shfl_xor(rs[r], off, 64);
#pragma unroll
        for (int r = 0; r < 4; ++r)
            l_run[r] = l_run[r] * al[r] + rs[r];

        // P -> LDS (bf16), then reload in A-fragment layout
#pragma unroll
        for (int ct = 0; ct < 4; ++ct)
#pragma unroll
            for (int r = 0; r < 4; ++r)
                p_s[w * 1152 + (g * 4 + r) * 72 + ct * 16 + ln] = f2bf(p[ct][r]);

#pragma unroll
        for (int dt = 0; dt < 6; ++dt)
#pragma unroll
            for (int r = 0; r < 4; ++r)
                acc_o[dt][r] *= al[r];

        asm volatile("s_waitcnt lgkmcnt(0)" ::: "memory");  // per-wave P write->read
        bf16x8 pf[2];
#pragma unroll
        for (int kb = 0; kb < 2; ++kb)
            pf[kb] = *(const bf16x8*)&p_s[w * 1152 + ln * 72 + kb * 32 + g * 8];
#pragma unroll
        for (int dt = 0; dt < 6; ++dt)
#pragma unroll
            for (int kb = 0; kb < 2; ++kb) {
                bf16x8 vf = *(const bf16x8*)&vt_s[(dt * 16 + ln) * 72 + kb * 32 + g * 8];
                acc_o[dt] = __builtin_amdgcn_mfma_f32_16x16x32_bf16(pf[kb], vf, acc_o[dt], 0, 0, 0);
            }
    }

    // epilogue: O/l, reverse-sparse scatter into ATT [4096][2304] bf16
    const int n_idx = inst / NH, h = inst - n_idx * NH;
#pragma unroll
    for (int r = 0; r < 4; ++r) {
        float inv = 1.0f / l_run[r];
        int gq = qb0 + w * 16 + g * 4 + r;
        size_t srow = ((size_t)(gq * 4 + n_idx)) * DIM + h * DH;
#pragma unroll
        for (int dt = 0; dt < 6; ++dt)
            ATT[srow + dt * 16 + ln] = f2bf(acc_o[dt][r] * inv);
    }
}

// ---------------- launch ----------------
extern "C" void kernel_launch(void* const* d_in, const int* in_sizes, int n_in,
                              void* d_out, int out_size, void* d_ws, size_t ws_size,
                              hipStream_t stream) {
    const float* hidden = (const float*)d_in[0];
    const float* wq = (const float*)d_in[1];
    const float* bq = (const float*)d_in[2];
    const float* wk = (const float*)d_in[3];
    const float* bk = (const float*)d_in[4];
    const float* wv = (const float*)d_in[5];
    const float* bv = (const float*)d_in[6];
    const float* wo = (const float*)d_in[7];
    const float* bo = (const float*)d_in[8];
    float* out = (float*)d_out;

    char* ws = (char*)d_ws;
    ushort_t* Xb  = (ushort_t*)ws;                       // 4096x2304 bf16
    ushort_t* WTq = (ushort_t*)(ws + 18874368);
    ushort_t* WTk = WTq + (size_t)DIM * DIM;
    ushort_t* WTv = WTk + (size_t)DIM * DIM;
    ushort_t* WTo = WTv + (size_t)DIM * DIM;
    ushort_t* Qb  = WTo + (size_t)DIM * DIM;             // [4][24][1024][96]
    ushort_t* Kb  = Qb + (size_t)S_TOK * DIM;
    ushort_t* Vb  = Kb + (size_t)S_TOK * DIM;
    ushort_t* ATT = Vb + (size_t)S_TOK * DIM;            // [4096][2304] bf16
    // total ws use: ~137 MB

    cast_bf16_kernel<<<dim3(9216), dim3(256), 0, stream>>>(hidden, Xb, (S_TOK * DIM) / 4);

    dim3 tg(72, 72);
    wtrans_kernel<<<tg, 256, 0, stream>>>(wq, WTq, DIM);
    wtrans_kernel<<<tg, 256, 0, stream>>>(wk, WTk, DIM);
    wtrans_kernel<<<tg, 256, 0, stream>>>(wv, WTv, DIM);
    wtrans_kernel<<<tg, 256, 0, stream>>>(wo, WTo, DIM);

    dim3 gg(DIM / 128, S_TOK / 128);   // (18, 32)
    gemm_bt<0><<<gg, 256, 0, stream>>>(Xb, WTq, bq, Qb);
    gemm_bt<1><<<gg, 256, 0, stream>>>(Xb, WTk, bk, Kb);
    gemm_bt<2><<<gg, 256, 0, stream>>>(Xb, WTv, bv, Vb);

    attn_kernel<<<dim3(96, 16), 256, 0, stream>>>(Qb, Kb, Vb, ATT);

    gemm_bt<3><<<gg, 256, 0, stream>>>(ATT, WTo, bo, out);
}

// Round 2
// 418.563 us; speedup vs baseline: 1.2993x; 1.2993x over previous
//
#include <hip/hip_runtime.h>
#include <stdint.h>

// ---------------- problem constants (b=1, f=8, h=16, w=32) ----------------
#define S_TOK 4096
#define DIM   2304
#define NH    24
#define DH    96
#define GQ    1024     // sparse sequence length (4096/4)
#define KDIM  2304

typedef unsigned short ushort_t;
typedef __attribute__((ext_vector_type(8))) short bf16x8;   // 8 bf16 = 4 VGPRs
typedef __attribute__((ext_vector_type(4))) float f32x4;

__device__ __forceinline__ ushort_t f2bf(float x) {
    union { float f; uint32_t u; } c; c.f = x;
    uint32_t u = c.u + 0x7FFFu + ((c.u >> 16) & 1u);   // RNE
    return (ushort_t)(u >> 16);
}

// ---------------- elementwise cast fp32 -> bf16 ----------------
__global__ __launch_bounds__(256) void cast_bf16_kernel(const float* __restrict__ in,
                                                        ushort_t* __restrict__ out, int n4) {
    int i = blockIdx.x * 256 + threadIdx.x;
    if (i >= n4) return;
    float4 v = ((const float4*)in)[i];
    ushort4 o;
    o.x = f2bf(v.x); o.y = f2bf(v.y); o.z = f2bf(v.z); o.w = f2bf(v.w);
    ((ushort4*)out)[i] = o;
}

// ---------------- W [k][n] fp32 -> WT [n][k] bf16 (tiled transpose) ----------------
__global__ __launch_bounds__(256) void wtrans_kernel(const float* __restrict__ W,
                                                     ushort_t* __restrict__ WT, int dim) {
    __shared__ float tile[32][33];
    const int bx = blockIdx.x * 32;   // n block
    const int by = blockIdx.y * 32;   // k block
    const int tx = threadIdx.x & 31, ty = threadIdx.x >> 5;
#pragma unroll
    for (int i = 0; i < 4; ++i)
        tile[ty + i*8][tx] = W[(size_t)(by + ty + i*8) * dim + bx + tx];
    __syncthreads();
#pragma unroll
    for (int i = 0; i < 4; ++i)
        WT[(size_t)(bx + ty + i*8) * dim + by + tx] = f2bf(tile[tx][ty + i*8]);
}

// ---------------- GEMM: C[m][n] = sum_k A[m][k]*Bt[n][k] + bias[n] ----------------
//   MODE 0: Q -> rope3d * 1/sqrt(96) -> [4][24][1024][96] bf16
//   MODE 1: K -> rope3d              -> [4][24][1024][96] bf16
//   MODE 2: V -> reorder + transpose -> [4][24][96][1024] bf16 (V^T layout)
//   MODE 3: fp32 row-major C (final output)
#define GLDS(gp, lp) __builtin_amdgcn_global_load_lds( \
    (const __attribute__((address_space(1))) void*)(gp), \
    (__attribute__((address_space(3))) void*)(lp), 16, 0, 0)

template<int MODE>
__global__ __launch_bounds__(256) void gemm_bt(const ushort_t* __restrict__ A,
                                               const ushort_t* __restrict__ Bt,
                                               const float* __restrict__ bias,
                                               void* __restrict__ outp) {
    constexpr int K = KDIM;
    __shared__ ushort_t a_s[128 * 32];
    __shared__ ushort_t b_s[128 * 32];
    const int t  = threadIdx.x;
    const int l  = t & 63, w = t >> 6;
    const int wr = w >> 1, wc = w & 1;
    const int g  = l >> 4, ln = l & 15;
    // XCD-aware bijective swizzle: 576 blocks, 72 per XCD (576 % 8 == 0)
    const int lin = blockIdx.y * gridDim.x + blockIdx.x;
    const int swz = (lin & 7) * 72 + (lin >> 3);
    const int m0 = (swz / 18) * 128, n0 = (swz % 18) * 128;

    const ushort_t* Ab = A  + (size_t)(m0 + (t >> 2)) * K + (t & 3) * 8;
    const ushort_t* Bb = Bt + (size_t)(n0 + (t >> 2)) * K + (t & 3) * 8;
    ushort_t* a_d0 = a_s + t * 8;
    ushort_t* a_d1 = a_s + 2048 + t * 8;
    ushort_t* b_d0 = b_s + t * 8;
    ushort_t* b_d1 = b_s + 2048 + t * 8;
    const size_t rstep = (size_t)64 * K;

    f32x4 acc[4][4] = {};

    for (int k0 = 0; k0 < K; k0 += 32) {
        __syncthreads();
        GLDS(Ab + k0,         a_d0);
        GLDS(Ab + rstep + k0, a_d1);
        GLDS(Bb + k0,         b_d0);
        GLDS(Bb + rstep + k0, b_d1);
        __syncthreads();
        bf16x8 av[4], bv[4];
#pragma unroll
        for (int i = 0; i < 4; ++i)
            av[i] = *(const bf16x8*)&a_s[(wr*64 + i*16 + ln) * 32 + g * 8];
#pragma unroll
        for (int j = 0; j < 4; ++j)
            bv[j] = *(const bf16x8*)&b_s[(wc*64 + j*16 + ln) * 32 + g * 8];
#pragma unroll
        for (int i = 0; i < 4; ++i)
#pragma unroll
            for (int j = 0; j < 4; ++j)
                acc[i][j] = __builtin_amdgcn_mfma_f32_16x16x32_bf16(av[i], bv[j], acc[i][j], 0, 0, 0);
    }

    if constexpr (MODE == 3) {
        float* C = (float*)outp;
#pragma unroll
        for (int i = 0; i < 4; ++i) {
            int mb = m0 + wr*64 + i*16 + g*4;
#pragma unroll
            for (int j = 0; j < 4; ++j) {
                int n = n0 + wc*64 + j*16 + ln;
                float bb = bias[n];
#pragma unroll
                for (int r = 0; r < 4; ++r)
                    C[(size_t)(mb + r) * DIM + n] = acc[i][j][r] + bb;
            }
        }
    } else if constexpr (MODE == 2) {
        // V^T: [inst = (m&3)*24+h][d][q = m>>2]
        ushort_t* O = (ushort_t*)outp;
#pragma unroll
        for (int i = 0; i < 4; ++i) {
            int mb = m0 + wr*64 + i*16 + g*4;     // mb % 4 == 0
            int q  = mb >> 2;
#pragma unroll
            for (int j = 0; j < 4; ++j) {
                int n = n0 + wc*64 + j*16 + ln;
                int h = n / DH, d = n - h * DH;
                float bb = bias[n];
#pragma unroll
                for (int r = 0; r < 4; ++r) {
                    // m = mb + r -> inst = r*24 + h, q = mb>>2
                    O[(size_t)(r * NH + h) * (DH * GQ) + (size_t)d * GQ + q] = f2bf(acc[i][j][r] + bb);
                }
            }
        }
    } else {
        // Q (MODE 0) / K (MODE 1): fused 3D rope + sparse reorder.
        const float scq = (MODE == 0) ? 0.1020620726159658f : 1.0f;  // 1/sqrt(96)
        ushort_t* O = (ushort_t*)outp;
#pragma unroll
        for (int i = 0; i < 4; ++i) {
            int mb = m0 + wr*64 + i*16 + g*4;
#pragma unroll
            for (int jp = 0; jp < 2; ++jp) {
                int j  = jp * 2;
                int n1 = n0 + wc*64 + j*16 + ln;       // even absolute 16-tile -> d1%32 < 16
                int h  = n1 / DH, d1 = n1 - h * DH;    // d1 in {0..15,32..47,64..79}
                int sec = d1 >> 5, f = d1 & 15;
                float invf = __expf((float)f * -0.5756462732485114f);  // 10000^(-f/16)
                float b1 = bias[n1], b2 = bias[n1 + 16];
#pragma unroll
                for (int r = 0; r < 4; ++r) {
                    int m = mb + r;                          // token index
                    int pos = (sec == 0) ? (m >> 9) : (sec == 1) ? ((m >> 5) & 15) : (m & 31);
                    float ang = (float)pos * invf;
                    float sn, cs;
                    __sincosf(ang, &sn, &cs);
                    float v1 = acc[i][j][r]     + b1;
                    float v2 = acc[i][j + 1][r] + b2;
                    float o1 = (v1 * cs - v2 * sn) * scq;
                    float o2 = (v2 * cs + v1 * sn) * scq;
                    size_t base = ((size_t)((m & 3) * NH + h)) * (GQ * DH) + (size_t)(m >> 2) * DH;
                    O[base + d1]      = f2bf(o1);
                    O[base + d1 + 16] = f2bf(o2);
                }
            }
        }
    }
}

// ---------------- flash attention: 96 instances of [1024,96], V^T input ----------------
// block = (instance, 128 q rows), 4 waves x 32 rows; KV tile = 64 keys.
// LDS chunk-major layouts: every MFMA fragment = one contiguous 16B chunk.
__global__ __launch_bounds__(256, 3) void attn_kernel(const ushort_t* __restrict__ Qb,
                                                      const ushort_t* __restrict__ Kb,
                                                      const ushort_t* __restrict__ Vt,
                                                      ushort_t* __restrict__ ATT) {
    __shared__ ushort_t k_s[2][12 * 64 * 8];   // [buf][d-chunk][key][8]   12 KB x2
    __shared__ ushort_t v_s[8 * 96 * 8];       // [key-chunk][d][8]        12 KB
    __shared__ ushort_t p_s[4][8 * 16 * 8];    // per-wave [key-chunk][q][8] 2 KB x4

    const int t = threadIdx.x, l = t & 63, w = t >> 6, g = l >> 4, ln = l & 15;
    // XCD-bijective swizzle: 768 blocks -> 96 per XCD = 12 whole instances
    const int lin  = blockIdx.x;
    const int swz  = (lin & 7) * 96 + (lin >> 3);
    const int inst = swz >> 3;            // 0..95
    const int qb0  = (swz & 7) * 128;
    const int n_idx = inst / NH, h = inst - n_idx * NH;

    const ushort_t* Qi = Qb + (size_t)inst * (GQ * DH);
    const ushort_t* Ki = Kb + (size_t)inst * (GQ * DH);
    const ushort_t* Vi = Vt + (size_t)inst * (DH * GQ);   // [96][1024]

    // ---- staging (global_load_lds, linear dest = chunk index * 16B) ----
    auto stageK = [&](int kt, int b) {
#pragma unroll
        for (int it = 0; it < 3; ++it) {
            int P = t + it * 256;              // 0..767 = [c<12][key<64]
            int c = P >> 6, key = P & 63;
            GLDS(Ki + (size_t)(kt * 64 + key) * DH + c * 8, &k_s[b][P * 8]);
        }
    };
    auto stageV = [&](int kt) {
#pragma unroll
        for (int it = 0; it < 3; ++it) {
            int P = t + it * 256;              // 0..767 = [c<8][d<96]
            int c = P / 96, d = P - c * 96;
            GLDS(Vi + (size_t)d * GQ + kt * 64 + c * 8, &v_s[P * 8]);
        }
    };

    // hoist Q fragments (A operand); Q already carries 1/sqrt(96)
    bf16x8 qf[2][3];
#pragma unroll
    for (int qt = 0; qt < 2; ++qt)
#pragma unroll
        for (int ks = 0; ks < 3; ++ks)
            qf[qt][ks] = *(const bf16x8*)(Qi + (size_t)(qb0 + w*32 + qt*16 + ln) * DH + ks*32 + g*8);

    float m_run[2][4], l_run[2][4];
#pragma unroll
    for (int qt = 0; qt < 2; ++qt)
#pragma unroll
        for (int r = 0; r < 4; ++r) { m_run[qt][r] = -3.0e38f; l_run[qt][r] = 0.f; }
    f32x4 acc_o[2][6] = {};

    stageK(0, 0);
    stageV(0);
    __syncthreads();            // drains vmcnt -> K0,V0 resident

    int cur = 0;
    for (int kt = 0; kt < 16; ++kt) {
        stageK((kt + 1) & 15, cur ^ 1);        // prefetch next K (3 GLDS, stays in flight)

#pragma unroll
        for (int qt = 0; qt < 2; ++qt) {
            // S = Q K^T : C layout col=key(ln), row=q(g*4+r)
            f32x4 sc[4] = {};
#pragma unroll
            for (int ct = 0; ct < 4; ++ct)
#pragma unroll
                for (int ks = 0; ks < 3; ++ks) {
                    bf16x8 kf = *(const bf16x8*)&k_s[cur][((ks*4 + g) * 64 + ct*16 + ln) * 8];
                    sc[ct] = __builtin_amdgcn_mfma_f32_16x16x32_bf16(qf[qt][ks], kf, sc[ct], 0, 0, 0);
                }

            // online softmax across 16 lanes (keys) x 4 regs
            float mx[4];
#pragma unroll
            for (int r = 0; r < 4; ++r)
                mx[r] = fmaxf(fmaxf(sc[0][r], sc[1][r]), fmaxf(sc[2][r], sc[3][r]));
#pragma unroll
            for (int off = 1; off < 16; off <<= 1)
#pragma unroll
                for (int r = 0; r < 4; ++r)
                    mx[r] = fmaxf(mx[r], __shfl_xor(mx[r], off, 64));
            float al[4], rs[4], p[4][4];
#pragma unroll
            for (int r = 0; r < 4; ++r) {
                float mn = fmaxf(m_run[qt][r], mx[r]);
                al[r] = __expf(m_run[qt][r] - mn);
                m_run[qt][r] = mn;
                rs[r] = 0.f;
            }
#pragma unroll
            for (int ct = 0; ct < 4; ++ct)
#pragma unroll
                for (int r = 0; r < 4; ++r) {
                    p[ct][r] = __expf(sc[ct][r] - m_run[qt][r]);
                    rs[r] += p[ct][r];
                }
#pragma unroll
            for (int off = 1; off < 16; off <<= 1)
#pragma unroll
                for (int r = 0; r < 4; ++r)
                    rs[r] += __shfl_xor(rs[r], off, 64);
#pragma unroll
            for (int r = 0; r < 4; ++r)
                l_run[qt][r] = l_run[qt][r] * al[r] + rs[r];

            // P -> per-wave LDS, chunk-major [key-chunk][q][8]
#pragma unroll
            for (int ct = 0; ct < 4; ++ct)
#pragma unroll
                for (int r = 0; r < 4; ++r)
                    p_s[w][((ct*2 + (ln >> 3)) * 16 + g*4 + r) * 8 + (ln & 7)] = f2bf(p[ct][r]);

#pragma unroll
            for (int dt = 0; dt < 6; ++dt)
#pragma unroll
                for (int r = 0; r < 4; ++r)
                    acc_o[qt][dt][r] *= al[r];

            if (qt == 0) {
                // own V loads done (3 K-prefetch remain in flight), then cross-wave barrier
                asm volatile("s_waitcnt vmcnt(3)" ::: "memory");
                __builtin_amdgcn_s_barrier();
                asm volatile("" ::: "memory");
                __builtin_amdgcn_sched_barrier(0);
            }

            asm volatile("s_waitcnt lgkmcnt(0)" ::: "memory");  // per-wave P write->read
            bf16x8 pf[2];
#pragma unroll
            for (int kb = 0; kb < 2; ++kb)
                pf[kb] = *(const bf16x8*)&p_s[w][((kb*4 + g) * 16 + ln) * 8];
#pragma unroll
            for (int dt = 0; dt < 6; ++dt)
#pragma unroll
                for (int kb = 0; kb < 2; ++kb) {
                    bf16x8 vf = *(const bf16x8*)&v_s[((kb*4 + g) * 96 + dt*16 + ln) * 8];
                    acc_o[qt][dt] = __builtin_amdgcn_mfma_f32_16x16x32_bf16(pf[kb], vf, acc_o[qt][dt], 0, 0, 0);
                }
        }

        __syncthreads();         // drains vmcnt(0): next K ready; all waves done with v_s & k_s[cur]
        if (kt < 15) stageV(kt + 1);
        cur ^= 1;
    }

    // epilogue: O/l, reverse-sparse scatter into ATT [4096][2304] bf16
#pragma unroll
    for (int qt = 0; qt < 2; ++qt)
#pragma unroll
        for (int r = 0; r < 4; ++r) {
            float inv = 1.0f / l_run[qt][r];
            int gq = qb0 + w*32 + qt*16 + g*4 + r;
            size_t srow = ((size_t)(gq * 4 + n_idx)) * DIM + h * DH;
#pragma unroll
            for (int dt = 0; dt < 6; ++dt)
                ATT[srow + dt*16 + ln] = f2bf(acc_o[qt][dt][r] * inv);
        }
}

// ---------------- launch ----------------
extern "C" void kernel_launch(void* const* d_in, const int* in_sizes, int n_in,
                              void* d_out, int out_size, void* d_ws, size_t ws_size,
                              hipStream_t stream) {
    const float* hidden = (const float*)d_in[0];
    const float* wq = (const float*)d_in[1];
    const float* bq = (const float*)d_in[2];
    const float* wk = (const float*)d_in[3];
    const float* bk = (const float*)d_in[4];
    const float* wv = (const float*)d_in[5];
    const float* bv = (const float*)d_in[6];
    const float* wo = (const float*)d_in[7];
    const float* bo = (const float*)d_in[8];
    float* out = (float*)d_out;

    char* ws = (char*)d_ws;
    ushort_t* Xb  = (ushort_t*)ws;                       // 4096x2304 bf16
    ushort_t* WTq = (ushort_t*)(ws + 18874368);
    ushort_t* WTk = WTq + (size_t)DIM * DIM;
    ushort_t* WTv = WTk + (size_t)DIM * DIM;
    ushort_t* WTo = WTv + (size_t)DIM * DIM;
    ushort_t* Qb  = WTo + (size_t)DIM * DIM;             // [4][24][1024][96]
    ushort_t* Kb  = Qb + (size_t)S_TOK * DIM;            // [4][24][1024][96]
    ushort_t* Vtb = Kb + (size_t)S_TOK * DIM;            // [4][24][96][1024]  (V^T)
    ushort_t* ATT = Vtb + (size_t)S_TOK * DIM;           // [4096][2304] bf16

    cast_bf16_kernel<<<dim3(9216), dim3(256), 0, stream>>>(hidden, Xb, (S_TOK * DIM) / 4);

    dim3 tg(72, 72);
    wtrans_kernel<<<tg, 256, 0, stream>>>(wq, WTq, DIM);
    wtrans_kernel<<<tg, 256, 0, stream>>>(wk, WTk, DIM);
    wtrans_kernel<<<tg, 256, 0, stream>>>(wv, WTv, DIM);
    wtrans_kernel<<<tg, 256, 0, stream>>>(wo, WTo, DIM);

    dim3 gg(DIM / 128, S_TOK / 128);   // (18, 32) = 576 blocks
    gemm_bt<0><<<gg, 256, 0, stream>>>(Xb, WTq, bq, Qb);
    gemm_bt<1><<<gg, 256, 0, stream>>>(Xb, WTk, bk, Kb);
    gemm_bt<2><<<gg, 256, 0, stream>>>(Xb, WTv, bv, Vtb);

    attn_kernel<<<dim3(768), 256, 0, stream>>>(Qb, Kb, Vtb, ATT);

    gemm_bt<3><<<gg, 256, 0, stream>>>(ATT, WTo, bo, out);
}